// Round 1
// baseline (56.214 us; speedup 1.0000x reference)
//
#include <hip/hip_runtime.h>

// ConvDatapath: bit-serial crossbar conv with per-chunk ADC quantization.
// Nx = B*H*W = 6272 im2col rows, Ny = COUT = 128, K = 576 (5 chunks of 116).
// 8-bit unsigned per-row quantization, 4 slices x 2 bits each side.

#define NX    6272
#define NY    128
#define KDIM  576
#define NCH   5
#define NPB   116
#define RT    392   // NX/16 row tiles
#define CTN   8     // NY/16 col tiles

typedef int i32x4 __attribute__((ext_vector_type(4)));

// MFMA i8 16x16x64 fragment byte offset.
// Fragment layout: lane l holds row (l&15), k = 16*(l>>4)+j (j=0..15),
// split into ks=0/1 for k<64 / k>=64. tile-major storage:
// [chunk][tile][ks][lane][j]
__device__ __forceinline__ int frag_off(int chunk, int tile, int ntile,
                                        int kk, int rowInTile) {
    int ks   = kk >> 6;
    int lgrp = (kk >> 4) & 3;
    int j    = kk & 15;
    int ln   = lgrp * 16 + rowInTile;
    return (((chunk * ntile + tile) * 2 + ks) * 64 + ln) * 16 + j;
}

__device__ __forceinline__ i32x4 slice2b(i32x4 v, int sh) {
    i32x4 r;
    r[0] = (int)(((unsigned)v[0] >> sh) & 0x03030303u);
    r[1] = (int)(((unsigned)v[1] >> sh) & 0x03030303u);
    r[2] = (int)(((unsigned)v[2] >> sh) & 0x03030303u);
    r[3] = (int)(((unsigned)v[3] >> sh) & 0x03030303u);
    return r;
}

// ---------------- kernel 1: weight quantization ----------------
// w: [128][576] row-major (COUT x CIN*KH*KW) — already flat rows.
// one wave per row; lane handles 9 contiguous elements.
__global__ __launch_bounds__(256) void k_wquant(
    const float* __restrict__ w, unsigned char* __restrict__ Wq,
    float* __restrict__ w_scale, float* __restrict__ w_offs,
    float* __restrict__ w_sum)
{
    int row  = blockIdx.x * 4 + (threadIdx.x >> 6);   // 32 blocks * 4 waves
    int lane = threadIdx.x & 63;
    const float* wr = w + row * KDIM;

    float v[9];
#pragma unroll
    for (int r = 0; r < 9; r++) v[r] = wr[lane * 9 + r];

    float mn = v[0], mx = v[0], sm = 0.f;
#pragma unroll
    for (int r = 0; r < 9; r++) { mn = fminf(mn, v[r]); mx = fmaxf(mx, v[r]); sm += v[r]; }
#pragma unroll
    for (int off = 32; off > 0; off >>= 1) {
        mn = fminf(mn, __shfl_xor(mn, off));
        mx = fmaxf(mx, __shfl_xor(mx, off));
        sm += __shfl_xor(sm, off);
    }
    float step = (mx - mn) / 255.0f;
    if (lane == 0) { w_scale[row] = step; w_offs[row] = mn; w_sum[row] = sm; }

    int ctile = row >> 4, rl = row & 15;
#pragma unroll
    for (int r = 0; r < 9; r++) {
        int t = lane * 9 + r;
        int q = (int)rintf((v[r] - mn) / step);
        q = q < 0 ? 0 : (q > 255 ? 255 : q);
        int chunk = t / NPB, kk = t - chunk * NPB;
        Wq[frag_off(chunk, ctile, CTN, kk, rl)] = (unsigned char)q;
    }
    // zero the per-chunk K padding: chunks 0..3 pad kk 116..127 (12 each),
    // chunk 4 holds real k only up to kk=111 -> pad kk 112..127 (16).
    {
        int chunk, kk;
        if (lane < 48) { chunk = lane / 12; kk = NPB + lane % 12; }
        else           { chunk = 4;        kk = 112 + (lane - 48); }
        Wq[frag_off(chunk, ctile, CTN, kk, rl)] = 0;
    }
}

// ---------------- kernel 2: im2col + x quantization ----------------
// one block per (b,h) stripe; LDS holds x[b][:, h-1..h+1, :].
// wave handles output rows w, w+4, ... ; lane == cin.
__global__ __launch_bounds__(256) void k_xquant(
    const float* __restrict__ x, unsigned char* __restrict__ Xq,
    float* __restrict__ x_scale, float* __restrict__ x_offs,
    float* __restrict__ x_sum)
{
    __shared__ float xs[64][169];   // [cin][kh*56+ww], stride 169 to dodge bank conflicts
    int bh = blockIdx.x;
    int b = bh / 56, h = bh - (bh / 56) * 56;

    for (int i = threadIdx.x; i < 64 * 168; i += 256) {
        int cin = i / 168, rem = i - cin * 168;
        int kh = rem / 56, ww = rem - kh * 56;
        int hh = h - 1 + kh;
        float v = 0.f;
        if (hh >= 0 && hh < 56) v = x[((b * 64 + cin) * 56 + hh) * 56 + ww];
        xs[cin][rem] = v;
    }
    __syncthreads();

    int wave = threadIdx.x >> 6, lane = threadIdx.x & 63;
    for (int w = wave; w < 56; w += 4) {
        float v[9];
#pragma unroll
        for (int kh = 0; kh < 3; kh++)
#pragma unroll
            for (int kw = 0; kw < 3; kw++) {
                int ww = w - 1 + kw;
                v[kh * 3 + kw] = (ww >= 0 && ww < 56) ? xs[lane][kh * 56 + ww] : 0.f;
            }
        float mn = v[0], mx = v[0], sm = 0.f;
#pragma unroll
        for (int r = 0; r < 9; r++) { mn = fminf(mn, v[r]); mx = fmaxf(mx, v[r]); sm += v[r]; }
#pragma unroll
        for (int off = 32; off > 0; off >>= 1) {
            mn = fminf(mn, __shfl_xor(mn, off));
            mx = fmaxf(mx, __shfl_xor(mx, off));
            sm += __shfl_xor(sm, off);
        }
        float step = (mx - mn) / 255.0f;
        int xrow = b * 3136 + h * 56 + w;
        if (lane == 0) { x_scale[xrow] = step; x_offs[xrow] = mn; x_sum[xrow] = sm; }

        int rtile = xrow >> 4, rl = xrow & 15;
#pragma unroll
        for (int r = 0; r < 9; r++) {
            int t = lane * 9 + r;
            int q = (int)rintf((v[r] - mn) / step);
            q = q < 0 ? 0 : (q > 255 ? 255 : q);
            int chunk = t / NPB, kk = t - chunk * NPB;
            Xq[frag_off(chunk, rtile, RT, kk, rl)] = (unsigned char)q;
        }
        {
            int chunk, kk;
            if (lane < 48) { chunk = lane / 12; kk = NPB + lane % 12; }
            else           { chunk = 4;        kk = 112 + (lane - 48); }
            Xq[frag_off(chunk, rtile, RT, kk, rl)] = 0;
        }
    }
}

// ---------------- kernel 3: crossbar GEMM + ADC + dequant ----------------
// one wave per 16x16 output tile. No LDS: operands are pre-laid-out in
// fragment order, so each load is one coalesced global_load_dwordx4.
__global__ __launch_bounds__(256) void k_main(
    const unsigned char* __restrict__ Xq, const unsigned char* __restrict__ Wq,
    const float* __restrict__ x_scale, const float* __restrict__ x_offs,
    const float* __restrict__ x_sum,
    const float* __restrict__ w_scale, const float* __restrict__ w_offs,
    const float* __restrict__ w_sum,
    float* __restrict__ out)
{
    int wid   = blockIdx.x * 4 + (threadIdx.x >> 6);  // 0..3135
    int rtile = wid >> 3;                             // 0..391
    int ctile = wid & 7;                              // 0..7
    int lane  = threadIdx.x & 63;

    i32x4 acc = {0, 0, 0, 0};
    const i32x4 zero = {0, 0, 0, 0};

    for (int chunk = 0; chunk < NCH; chunk++) {
        const i32x4* Ab = (const i32x4*)(Xq + ((chunk * RT + rtile) * 2 * 64 + lane) * 16);
        const i32x4* Bb = (const i32x4*)(Wq + ((chunk * CTN + ctile) * 2 * 64 + lane) * 16);
        i32x4 ar0 = Ab[0], ar1 = Ab[64];   // ks=0, ks=1 (stride 1024B)
        i32x4 br0 = Bb[0], br1 = Bb[64];

        i32x4 bs[4][2];
#pragma unroll
        for (int ws = 0; ws < 4; ws++) {
            bs[ws][0] = slice2b(br0, 6 - 2 * ws);
            bs[ws][1] = slice2b(br1, 6 - 2 * ws);
        }
#pragma unroll
        for (int is = 0; is < 4; is++) {
            int ish = 6 - 2 * is;
            i32x4 a0 = slice2b(ar0, ish);
            i32x4 a1 = slice2b(ar1, ish);
#pragma unroll
            for (int ws = 0; ws < 4; ws++) {
                i32x4 d = __builtin_amdgcn_mfma_i32_16x16x64_i8(a0, bs[ws][0], zero, 0, 0, 0);
                d = __builtin_amdgcn_mfma_i32_16x16x64_i8(a1, bs[ws][1], d, 0, 0, 0);
                int sh = ish + (6 - 2 * ws);
#pragma unroll
                for (int r = 0; r < 4; r++) {
                    int z = d[r];
                    z = z > 1024 ? 1024 : z;                 // ADC clip (z >= 0 always)
                    int r4 = (z + 1 + ((z >> 2) & 1)) & ~3;  // round-half-even to mult of 4
                    acc[r] += r4 << sh;                      // slice recombination 2^(ish+wsh)
                }
            }
        }
    }

    // epilogue: dequant + offset corrections, mirror reference op order
    int col = ctile * 16 + (lane & 15);
    float wsc = w_scale[col], wof = w_offs[col], wsm = w_sum[col];
    int rowb = rtile * 16 + ((lane >> 4) << 2);
#pragma unroll
    for (int r = 0; r < 4; r++) {
        int xrow = rowb + r;
        float t = ((float)acc[r] * x_scale[xrow]) * wsc;
        t = ((t + x_offs[xrow] * wsm) + wof * x_sum[xrow])
            - (x_offs[xrow] * wof) * 576.0f;
        int bb = xrow >= 3136 ? 1 : 0;
        int hw = xrow - bb * 3136;
        out[(bb * 128 + col) * 3136 + hw] = t;
    }
}

extern "C" void kernel_launch(void* const* d_in, const int* in_sizes, int n_in,
                              void* d_out, int out_size, void* d_ws, size_t ws_size,
                              hipStream_t stream) {
    const float* x = (const float*)d_in[0];   // [2][64][56][56]
    const float* w = (const float*)d_in[1];   // [128][64][3][3]
    float* out = (float*)d_out;               // [2][128][56][56]

    // workspace layout
    unsigned char* Xq = (unsigned char*)d_ws;          // 5*392*2*64*16 = 4,014,080
    unsigned char* Wq = Xq + 5 * RT * 2 * 64 * 16;     // 5*8*2*64*16  = 81,920
    float* x_scale = (float*)(Wq + 5 * CTN * 2 * 64 * 16);
    float* x_offs  = x_scale + NX;
    float* x_sum   = x_offs + NX;
    float* w_scale = x_sum + NX;
    float* w_offs  = w_scale + NY;
    float* w_sum   = w_offs + NY;

    hipLaunchKernelGGL(k_wquant, dim3(32), dim3(256), 0, stream,
                       w, Wq, w_scale, w_offs, w_sum);
    hipLaunchKernelGGL(k_xquant, dim3(112), dim3(256), 0, stream,
                       x, Xq, x_scale, x_offs, x_sum);
    hipLaunchKernelGGL(k_main, dim3(784), dim3(256), 0, stream,
                       Xq, Wq, x_scale, x_offs, x_sum, w_scale, w_offs, w_sum, out);
}

// Round 4
// 38.144 us; speedup vs baseline: 1.4737x; 1.4737x over previous
//
#include <hip/hip_runtime.h>

// ConvDatapath: bit-serial crossbar conv with per-chunk ADC quantization.
// k_quant: im2col + 8-bit unsigned quant of x (and w), writing MFMA-fragment-
//          ordered u8 via LDS staging (coalesced dwordx4 stores).
// k_main : i8 MFMA crossbar (operands SWAPPED: D = W x X so lane&15 = x-pos
//          -> coalesced output stores, no LDS, no barriers) + ADC + dequant.
// Nx = 6272 im2col rows, Ny = 128, K = 576 (5 chunks of 116).

#define NX    6272
#define NY    128
#define KDIM  576
#define NCH   5
#define NPB   116
#define RT    392   // NX/16 row tiles
#define CTN   8     // NY/16 col tiles

typedef int i32x4 __attribute__((ext_vector_type(4)));

// MFMA i8 16x16x64 fragment byte offset: [chunk][tile][ks][lane][j]
// lane l holds row (l&15), k = 16*(l>>4)+j, ks = k>=64.
__device__ __forceinline__ int frag_off(int chunk, int tile, int ntile,
                                        int kk, int rowInTile) {
    int ks   = kk >> 6;
    int lgrp = (kk >> 4) & 3;
    int j    = kk & 15;
    int ln   = lgrp * 16 + rowInTile;
    return (((chunk * ntile + tile) * 2 + ks) * 64 + ln) * 16 + j;
}

// tile-local fragment offset: [chunk][ks][ln][j] (2048 B per chunk)
__device__ __forceinline__ int stg_off(int chunk, int kk, int rl) {
    int ks   = kk >> 6;
    int lgrp = (kk >> 4) & 3;
    int j    = kk & 15;
    return (chunk * 2 + ks) * 1024 + (lgrp * 16 + rl) * 16 + j;
}

__device__ __forceinline__ i32x4 slice2b(i32x4 v, int sh) {
    i32x4 r;
    r[0] = (int)(((unsigned)v[0] >> sh) & 0x03030303u);
    r[1] = (int)(((unsigned)v[1] >> sh) & 0x03030303u);
    r[2] = (int)(((unsigned)v[2] >> sh) & 0x03030303u);
    r[3] = (int)(((unsigned)v[3] >> sh) & 0x03030303u);
    return r;
}

// ---------------- kernel 1: quantization (x tiles + folded w) ----------------
// one block per 16-row output tile (392 blocks).
__global__ __launch_bounds__(256) void k_quant(
    const float* __restrict__ x, const float* __restrict__ w,
    unsigned char* __restrict__ Xq, unsigned char* __restrict__ Wq,
    float* __restrict__ x_scale, float* __restrict__ x_offs, float* __restrict__ x_sum,
    float* __restrict__ w_scale, float* __restrict__ w_offs, float* __restrict__ w_sum)
{
    __shared__ float xs2[64 * 57];                 // [cin][kh*18+c], stride 57 vs banks
    __shared__ __align__(16) unsigned char stg[10240];  // fragment-ordered tile

    int rtile = blockIdx.x;                 // 0..391
    int b = rtile >= 196 ? 1 : 0;
    int prt = rtile - b * 196;
    int pos0 = prt * 16;                    // flat h*56+w of first row in tile
    const float* xb = x + (size_t)(b * 64) * 3136;

    // stage: xs2[cin][kh][c] = x[cin][h(g)-1+kh][w(g)] for g = pos0+c-1
    for (int i = threadIdx.x; i < 64 * 54; i += 256) {
        int cin = i / 54, rem = i - cin * 54;
        int kh = rem / 18;
        int g = pos0 + (rem - kh * 18) - 1;
        float vv = 0.f;
        if (g >= 0 && g < 3136) {
            int hg = g / 56, wg = g - hg * 56;
            int r = hg - 1 + kh;
            if (r >= 0 && r < 56) vv = xb[cin * 3136 + r * 56 + wg];
        }
        xs2[cin * 57 + rem] = vv;
    }
    __syncthreads();

    int wave = threadIdx.x >> 6, lane = threadIdx.x & 63;
#pragma unroll
    for (int qi = 0; qi < 4; qi++) {
        int i = wave * 4 + qi;              // row within tile, 0..15
        int pos = pos0 + i;
        int w_ = pos - (pos / 56) * 56;
        float v[9];
#pragma unroll
        for (int kh = 0; kh < 3; kh++)
#pragma unroll
            for (int kw = 0; kw < 3; kw++) {
                int ww = w_ - 1 + kw;
                v[kh * 3 + kw] = (ww >= 0 && ww < 56)
                               ? xs2[lane * 57 + kh * 18 + i + kw] : 0.f;
            }
        float mn = v[0], mx = v[0], sm = 0.f;
#pragma unroll
        for (int r = 0; r < 9; r++) { mn = fminf(mn, v[r]); mx = fmaxf(mx, v[r]); sm += v[r]; }
#pragma unroll
        for (int off = 32; off > 0; off >>= 1) {
            mn = fminf(mn, __shfl_xor(mn, off));
            mx = fmaxf(mx, __shfl_xor(mx, off));
            sm += __shfl_xor(sm, off);
        }
        float step = (mx - mn) / 255.0f;
        int xrow = rtile * 16 + i;
        if (lane == 0) { x_scale[xrow] = step; x_offs[xrow] = mn; x_sum[xrow] = sm; }
#pragma unroll
        for (int r = 0; r < 9; r++) {
            int t2 = lane * 9 + r;
            int q = (int)rintf((v[r] - mn) / step);
            q = q < 0 ? 0 : (q > 255 ? 255 : q);
            int chunk = t2 / NPB, kk = t2 - chunk * NPB;
            stg[stg_off(chunk, kk, i)] = (unsigned char)q;
        }
        {   // per-row K padding: chunks 0..3 pad kk 116..127, chunk 4 pads 112..127
            int chunk, kk;
            if (lane < 48) { chunk = lane / 12; kk = NPB + lane % 12; }
            else           { chunk = 4;        kk = 112 + (lane - 48); }
            stg[stg_off(chunk, kk, i)] = 0;
        }
    }
    __syncthreads();

    // blast the staged tile out, coalesced 16B per lane
    for (int idx = threadIdx.x; idx < 640; idx += 256) {
        int c = idx >> 7, off = (idx & 127) * 16;
        *(i32x4*)(Xq + (size_t)(c * RT + rtile) * 2048 + off) =
            *(const i32x4*)(stg + c * 2048 + off);
    }

    // folded weight quantization: blocks 0..127, wave 0, one row each
    if (rtile < NY && wave == 0) {
        int row = rtile;
        const float* wr = w + row * KDIM;
        float v[9];
#pragma unroll
        for (int r = 0; r < 9; r++) v[r] = wr[lane * 9 + r];
        float mn = v[0], mx = v[0], sm = 0.f;
#pragma unroll
        for (int r = 0; r < 9; r++) { mn = fminf(mn, v[r]); mx = fmaxf(mx, v[r]); sm += v[r]; }
#pragma unroll
        for (int off = 32; off > 0; off >>= 1) {
            mn = fminf(mn, __shfl_xor(mn, off));
            mx = fmaxf(mx, __shfl_xor(mx, off));
            sm += __shfl_xor(sm, off);
        }
        float step = (mx - mn) / 255.0f;
        if (lane == 0) { w_scale[row] = step; w_offs[row] = mn; w_sum[row] = sm; }
        int ctile = row >> 4, rl = row & 15;
#pragma unroll
        for (int r = 0; r < 9; r++) {
            int t2 = lane * 9 + r;
            int q = (int)rintf((v[r] - mn) / step);
            q = q < 0 ? 0 : (q > 255 ? 255 : q);
            int chunk = t2 / NPB, kk = t2 - chunk * NPB;
            Wq[frag_off(chunk, ctile, CTN, kk, rl)] = (unsigned char)q;
        }
        int chunk, kk;
        if (lane < 48) { chunk = lane / 12; kk = NPB + lane % 12; }
        else           { chunk = 4;        kk = 112 + (lane - 48); }
        Wq[frag_off(chunk, ctile, CTN, kk, rl)] = 0;
    }
}

// ---------------- kernel 2: crossbar GEMM + ADC + dequant ----------------
// one wave per 16x16 output tile. Operands swapped (A=W, B=X) so the C/D
// layout has col(lane&15) = x position -> direct coalesced stores.
__global__ __launch_bounds__(256) void k_main(
    const unsigned char* __restrict__ Xq, const unsigned char* __restrict__ Wq,
    const float* __restrict__ x_scale, const float* __restrict__ x_offs,
    const float* __restrict__ x_sum,
    const float* __restrict__ w_scale, const float* __restrict__ w_offs,
    const float* __restrict__ w_sum,
    float* __restrict__ out)
{
    int wid   = blockIdx.x * 4 + (threadIdx.x >> 6);  // 0..3135
    int rtile = wid >> 3;                             // 0..391 (x tiles)
    int ctile = wid & 7;                              // 0..7   (w tiles)
    int lane  = threadIdx.x & 63;

    i32x4 acc = {0, 0, 0, 0};
    const i32x4 zero = {0, 0, 0, 0};

    for (int chunk = 0; chunk < NCH; chunk++) {
        const i32x4* Ab = (const i32x4*)(Xq + ((chunk * RT + rtile) * 2 * 64 + lane) * 16);
        const i32x4* Bb = (const i32x4*)(Wq + ((chunk * CTN + ctile) * 2 * 64 + lane) * 16);
        i32x4 ar0 = Ab[0], ar1 = Ab[64];   // x fragment, ks=0/1
        i32x4 br0 = Bb[0], br1 = Bb[64];   // w fragment, ks=0/1

        i32x4 ws_sl[4][2];                  // w slices (the MFMA A operand)
#pragma unroll
        for (int ws = 0; ws < 4; ws++) {
            ws_sl[ws][0] = slice2b(br0, 6 - 2 * ws);
            ws_sl[ws][1] = slice2b(br1, 6 - 2 * ws);
        }
#pragma unroll
        for (int is = 0; is < 4; is++) {
            int ish = 6 - 2 * is;
            i32x4 b0 = slice2b(ar0, ish);   // x slices (the MFMA B operand)
            i32x4 b1 = slice2b(ar1, ish);
#pragma unroll
            for (int ws = 0; ws < 4; ws++) {
                i32x4 d = __builtin_amdgcn_mfma_i32_16x16x64_i8(ws_sl[ws][0], b0, zero, 0, 0, 0);
                d = __builtin_amdgcn_mfma_i32_16x16x64_i8(ws_sl[ws][1], b1, d, 0, 0, 0);
                int sh = ish + (6 - 2 * ws);
#pragma unroll
                for (int r = 0; r < 4; r++) {
                    int z = d[r];
                    z = z > 1024 ? 1024 : z;                 // ADC clip (z >= 0)
                    int r4 = (z + 1 + ((z >> 2) & 1)) & ~3;  // round-half-even to mult of 4
                    acc[r] += r4 << sh;                      // 2^(ish+wsh)
                }
            }
        }
    }

    // epilogue: D[row = w-row (g*4+r), col = x-row (cl)]; dequant mirrors
    // reference op order; stores are 4x64B coalesced runs per instruction.
    int cl = lane & 15, g = lane >> 4;
    int xrow = rtile * 16 + cl;
    float xs = x_scale[xrow], xo = x_offs[xrow], xsm = x_sum[xrow];
    int bb = rtile >= 196 ? 1 : 0;
    int hw = xrow - bb * 3136;
#pragma unroll
    for (int r = 0; r < 4; r++) {
        int wrow = ctile * 16 + g * 4 + r;
        float tt = ((float)acc[r] * xs) * w_scale[wrow];
        float res = ((tt + xo * w_sum[wrow]) + w_offs[wrow] * xsm)
                  - (xo * w_offs[wrow]) * 576.0f;
        out[(bb * 128 + wrow) * 3136 + hw] = res;
    }
}

extern "C" void kernel_launch(void* const* d_in, const int* in_sizes, int n_in,
                              void* d_out, int out_size, void* d_ws, size_t ws_size,
                              hipStream_t stream) {
    const float* x = (const float*)d_in[0];   // [2][64][56][56]
    const float* w = (const float*)d_in[1];   // [128][64][3][3]
    float* out = (float*)d_out;               // [2][128][56][56]

    unsigned char* Xq = (unsigned char*)d_ws;          // 5*392*2048 = 4,014,080 B
    unsigned char* Wq = Xq + 5 * RT * 2048;            // 5*8*2048   = 81,920 B
    float* x_scale = (float*)(Wq + 5 * CTN * 2048);
    float* x_offs  = x_scale + NX;
    float* x_sum   = x_offs + NX;
    float* w_scale = x_sum + NX;
    float* w_offs  = w_scale + NY;
    float* w_sum   = w_offs + NY;

    hipLaunchKernelGGL(k_quant, dim3(RT), dim3(256), 0, stream,
                       x, w, Xq, Wq, x_scale, x_offs, x_sum, w_scale, w_offs, w_sum);
    hipLaunchKernelGGL(k_main, dim3(784), dim3(256), 0, stream,
                       Xq, Wq, x_scale, x_offs, x_sum, w_scale, w_offs, w_sum, out);
}